// Round 1
// baseline (314.711 us; speedup 1.0000x reference)
//
#include <hip/hip_runtime.h>
#include <math.h>

#define NTAGS 64
#define DC4   64          // D/4 = 256/4 float4 chunks per row
#define ROWS_PER_BLOCK 128
#define RG    8           // rows per wave per group
#define NWAVES 4

__global__ __launch_bounds__(256, 1)
void lcl_main(const float* __restrict__ feat,
              const int*   __restrict__ labels,
              const float* __restrict__ lemb,
              float*       __restrict__ out)
{
    // proto4[dc*64 + t] = float4 of prototype t, dims [4dc..4dc+3], normalized.
    __shared__ float4 proto4[DC4 * NTAGS];          // 64 KiB
    __shared__ float4 fst[NWAVES][RG][DC4];         // 32 KiB per-wave row staging
    __shared__ float  part[4][NTAGS];
    __shared__ float  scl[NTAGS];

    const int tid  = threadIdx.x;
    const int lane = tid & 63;
    const int wv   = tid >> 6;

    // ---- Phase A: load label_emb transposed into LDS (write-coalesced) ----
    const float4* lemb4 = (const float4*)lemb;
    #pragma unroll
    for (int k = 0; k < 16; ++k) {
        int w  = k * 256 + tid;      // proto4 index = dc*64 + t
        int t  = w & 63;
        int dc = w >> 6;
        proto4[w] = lemb4[t * 64 + dc];
    }
    __syncthreads();

    // ---- Phase B: prototype norms ----
    {
        int t = tid & 63, p = tid >> 6;
        float ss = 0.f;
        #pragma unroll
        for (int j = 0; j < 16; ++j) {
            float4 q = proto4[(p * 16 + j) * 64 + t];
            ss += q.x*q.x + q.y*q.y + q.z*q.z + q.w*q.w;
        }
        part[p][t] = ss;
    }
    __syncthreads();
    if (tid < NTAGS) {
        float ss = part[0][tid] + part[1][tid] + part[2][tid] + part[3][tid];
        scl[tid] = 1.0f / fmaxf(sqrtf(ss), 1e-8f);   // cosine_similarity eps
    }
    __syncthreads();
    // ---- Phase C: scale prototypes in place ----
    {
        int t = tid & 63, p = tid >> 6;
        float s = scl[t];
        #pragma unroll
        for (int j = 0; j < 16; ++j) {
            int idx = (p * 16 + j) * 64 + t;
            float4 q = proto4[idx];
            q.x *= s; q.y *= s; q.z *= s; q.w *= s;
            proto4[idx] = q;
        }
    }
    __syncthreads();

    // ---- Main loop: each wave owns 32 rows, in 4 groups of 8 ----
    const float4* feat4 = (const float4*)feat;
    const int rowBase = blockIdx.x * ROWS_PER_BLOCK + wv * (ROWS_PER_BLOCK / NWAVES);
    float loss = 0.f;

    for (int g = 0; g < (ROWS_PER_BLOCK / NWAVES) / RG; ++g) {
        const int row0 = rowBase + g * RG;

        float4 v[RG];
        #pragma unroll
        for (int r = 0; r < RG; ++r)
            v[r] = feat4[(size_t)(row0 + r) * DC4 + lane];   // coalesced 1KB/row

        float nrm[RG];
        #pragma unroll
        for (int r = 0; r < RG; ++r) {
            float sq = v[r].x*v[r].x + v[r].y*v[r].y + v[r].z*v[r].z + v[r].w*v[r].w;
            #pragma unroll
            for (int o = 1; o < 64; o <<= 1) sq += __shfl_xor(sq, o, 64);
            nrm[r] = sq;                                     // ||f||^2, all lanes
            fst[wv][r][lane] = v[r];                         // stage row (conflict-free)
        }

        float acc[RG];
        #pragma unroll
        for (int r = 0; r < RG; ++r) acc[r] = 0.f;

        // lane t accumulates dot(row_r, proto_t); proto read contiguous (no conflict),
        // f read uniform-address (broadcast, no conflict).
        #pragma unroll 4
        for (int dc = 0; dc < DC4; ++dc) {
            float4 pt = proto4[dc * 64 + lane];
            #pragma unroll
            for (int r = 0; r < RG; ++r) {
                float4 fr = fst[wv][r][dc];
                acc[r] = fmaf(pt.x, fr.x, acc[r]);
                acc[r] = fmaf(pt.y, fr.y, acc[r]);
                acc[r] = fmaf(pt.z, fr.z, acc[r]);
                acc[r] = fmaf(pt.w, fr.w, acc[r]);
            }
        }

        #pragma unroll
        for (int r = 0; r < RG; ++r) {
            float sim = acc[r] / fmaxf(sqrtf(nrm[r]), 1e-12f);  // F.normalize eps
            int   lbl = labels[row0 + r];
            float e   = __expf(2.0f * sim);                     // inv_t = 1/0.5
            float en  = (lane == lbl) ? 0.f : e;
            #pragma unroll
            for (int o = 1; o < 64; o <<= 1) en += __shfl_xor(en, o, 64);
            float siml = __shfl(sim, lbl, 64);
            loss += __logf(en) - 2.0f * siml;                   // -log(pos/neg)
        }
    }

    if (lane == 0) atomicAdd(out, loss);   // all lanes hold identical loss
}

extern "C" void kernel_launch(void* const* d_in, const int* in_sizes, int n_in,
                              void* d_out, int out_size, void* d_ws, size_t ws_size,
                              hipStream_t stream) {
    const float* feat   = (const float*)d_in[0];
    const int*   labels = (const int*)d_in[1];
    const float* lemb   = (const float*)d_in[2];
    float*       out    = (float*)d_out;

    hipMemsetAsync(d_out, 0, sizeof(float), stream);

    const int nrows = in_sizes[1];                 // B*S = 131072
    const int grid  = nrows / ROWS_PER_BLOCK;      // 1024 blocks
    lcl_main<<<grid, 256, 0, stream>>>(feat, labels, lemb, out);
}

// Round 2
// 122.546 us; speedup vs baseline: 2.5681x; 2.5681x over previous
//
#include <hip/hip_runtime.h>
#include <math.h>

typedef __attribute__((ext_vector_type(8))) short bf16x8;
typedef __attribute__((ext_vector_type(4))) float f32x4;

#define NTAGS 64

// RNE f32 -> bf16 (bit trick, no NaN inputs here)
__device__ __forceinline__ short f2bf(float f) {
    unsigned u = __builtin_bit_cast(unsigned, f);
    u += 0x7fffu + ((u >> 16) & 1u);
    return (short)(u >> 16);
}

__global__ __launch_bounds__(256, 4)
void lcl_mfma(const float* __restrict__ feat,
              const int*   __restrict__ labels,
              const float* __restrict__ lemb,
              float*       __restrict__ out)
{
    // protoB[(ks*4+g)*64 + t] = bf16x8 of normalized proto t, k = ks*32+g*8 .. +7
    __shared__ bf16x8 protoB[2048];        // 32 KiB
    __shared__ float  part[4][NTAGS];
    __shared__ float  scl[NTAGS];

    const int tid  = threadIdx.x;
    const int lane = tid & 63;
    const int wv   = tid >> 6;
    const float4* lemb4 = (const float4*)lemb;

    // ---- proto norms ----
    {
        int t = tid & 63, p = tid >> 6;
        float ss = 0.f;
        #pragma unroll
        for (int j = 0; j < 16; ++j) {
            float4 q = lemb4[t * 64 + p * 16 + j];
            ss += q.x*q.x + q.y*q.y + q.z*q.z + q.w*q.w;
        }
        part[p][t] = ss;
    }
    __syncthreads();
    if (tid < NTAGS) {
        float ss = part[0][tid] + part[1][tid] + part[2][tid] + part[3][tid];
        scl[tid] = 1.0f / fmaxf(sqrtf(ss), 1e-8f);      // cosine_similarity eps
    }
    __syncthreads();

    // ---- stage normalized bf16 protos in B-fragment layout ----
    #pragma unroll
    for (int i = 0; i < 8; ++i) {
        int e = i * 256 + tid;          // 2048 entries of 16B
        int chunk = e >> 6, t = e & 63;
        float s = scl[t];
        float4 q0 = lemb4[t * 64 + chunk * 2];
        float4 q1 = lemb4[t * 64 + chunk * 2 + 1];
        bf16x8 pk;
        pk[0] = f2bf(q0.x * s); pk[1] = f2bf(q0.y * s);
        pk[2] = f2bf(q0.z * s); pk[3] = f2bf(q0.w * s);
        pk[4] = f2bf(q1.x * s); pk[5] = f2bf(q1.y * s);
        pk[6] = f2bf(q1.z * s); pk[7] = f2bf(q1.w * s);
        protoB[e] = pk;
    }
    __syncthreads();

    // ---- main: each wave does 2 row-tiles of 16 rows ----
    const int g = lane >> 4;       // k-group 0..3
    const int r = lane & 15;       // row within tile (A) / col within tile (B)
    const float4* feat4 = (const float4*)feat;
    const int w = blockIdx.x * 4 + wv;
    float wloss = 0.f;

    for (int ti = 0; ti < 2; ++ti) {
        const int r0 = (w * 2 + ti) * 16;

        f32x4 acc[4];
        #pragma unroll
        for (int ct = 0; ct < 4; ++ct) acc[ct] = (f32x4){0.f, 0.f, 0.f, 0.f};

        float sq = 0.f;
        #pragma unroll
        for (int ks = 0; ks < 8; ++ks) {
            // lane reads row r0+r, k = ks*32 + g*8 .. +7  (128B contiguous per row)
            const size_t base = (size_t)(r0 + r) * 64 + ks * 8 + g * 2;
            float4 q0 = feat4[base];
            float4 q1 = feat4[base + 1];
            sq += q0.x*q0.x + q0.y*q0.y + q0.z*q0.z + q0.w*q0.w
                + q1.x*q1.x + q1.y*q1.y + q1.z*q1.z + q1.w*q1.w;
            bf16x8 af;
            af[0] = f2bf(q0.x); af[1] = f2bf(q0.y);
            af[2] = f2bf(q0.z); af[3] = f2bf(q0.w);
            af[4] = f2bf(q1.x); af[5] = f2bf(q1.y);
            af[6] = f2bf(q1.z); af[7] = f2bf(q1.w);
            const int cbase = (ks * 4 + g) * 64;
            #pragma unroll
            for (int ct = 0; ct < 4; ++ct)
                acc[ct] = __builtin_amdgcn_mfma_f32_16x16x32_bf16(
                              af, protoB[cbase + ct * 16 + r], acc[ct], 0, 0, 0);
        }

        // row norm: lanes {r, r+16, r+32, r+48} hold disjoint k-partials of row r
        sq += __shfl_xor(sq, 16, 64);
        sq += __shfl_xor(sq, 32, 64);
        float rn = 1.0f / fmaxf(sqrtf(sq), 1e-12f);     // F.normalize eps

        // epilogue: C layout col=lane&15 (tag within ct), row=(lane>>4)*4+reg
        #pragma unroll
        for (int reg = 0; reg < 4; ++reg) {
            const int rowi = g * 4 + reg;               // row within tile
            float rr  = __shfl(rn, rowi, 64);
            int   lbl = labels[r0 + rowi];
            float en = 0.f, pos = 0.f;
            #pragma unroll
            for (int ct = 0; ct < 4; ++ct) {
                float sim = acc[ct][reg] * rr;
                float e   = __expf(2.0f * sim);         // inv_t = 1/0.5
                bool  m   = (lbl == ct * 16 + r);
                en  += m ? 0.f : e;
                pos += m ? 2.0f * sim : 0.f;
            }
            #pragma unroll
            for (int o = 1; o < 16; o <<= 1) {
                en  += __shfl_xor(en,  o, 64);
                pos += __shfl_xor(pos, o, 64);
            }
            wloss += __logf(en) - pos;                  // -log(pos/neg)
        }
    }

    // groups hold identical copies; sum across the 4 groups, add once
    wloss += __shfl_xor(wloss, 16, 64);
    wloss += __shfl_xor(wloss, 32, 64);
    if (lane == 0) atomicAdd(out, wloss);
}

extern "C" void kernel_launch(void* const* d_in, const int* in_sizes, int n_in,
                              void* d_out, int out_size, void* d_ws, size_t ws_size,
                              hipStream_t stream) {
    const float* feat   = (const float*)d_in[0];
    const int*   labels = (const int*)d_in[1];
    const float* lemb   = (const float*)d_in[2];
    float*       out    = (float*)d_out;

    hipMemsetAsync(d_out, 0, sizeof(float), stream);

    const int nrows = in_sizes[1];                 // B*S = 131072
    const int grid  = nrows / 128;                 // 4 waves * 2 tiles * 16 rows
    lcl_mfma<<<grid, 256, 0, stream>>>(feat, labels, lemb, out);
}